// Round 14
// baseline (791.843 us; speedup 1.0000x reference)
//
#include <hip/hip_runtime.h>
#include <hip/hip_bf16.h>

// ---------------------------------------------------------------------------
// rnn_decoder: B=256 T=256 H=1024 E=512 V=32000 BN=512
// out = [pred (256x32000) | h1 (2x256x1024) | attn (256x256)]  (f32)
// All GEMMs bf16 MFMA (16x16x32), consistent assumed k-mapping for A and B
// fragments => correctness independent of HW internal K ordering. C layout:
// col=lane&15, row=(lane>>4)*4+reg (HW-verified m89).
// ---------------------------------------------------------------------------

typedef unsigned short u16;
typedef unsigned int u32;
typedef float f32x4 __attribute__((ext_vector_type(4)));
typedef u32 u32x4 __attribute__((ext_vector_type(4)));
typedef __bf16 bf16x8 __attribute__((ext_vector_type(8)));
typedef short s16x8 __attribute__((ext_vector_type(8)));

__device__ __forceinline__ u16 f2bf(float x) {
  u32 u = __float_as_uint(x);
  u += 0x7fffu + ((u >> 16) & 1u);
  return (u16)(u >> 16);
}
__device__ __forceinline__ u32 pack2(float a, float b) {
  return (u32)f2bf(a) | ((u32)f2bf(b) << 16);
}
// HW RTNE f32->bf16 pair (compiler emits v_cvt_pk_bf16_f32)
__device__ __forceinline__ u32 cvt2(float a, float b) {
  union { __bf16 h[2]; u32 w; } u;
  u.h[0] = (__bf16)a; u.h[1] = (__bf16)b;
  return u.w;
}
__device__ __forceinline__ float bf2f(u16 v) {
  return __uint_as_float((u32)v << 16);
}
__device__ __forceinline__ f32x4 mfma_bf16(s16x8 a, s16x8 b, f32x4 c) {
  union { s16x8 s; bf16x8 b; } ua, ub;
  ua.s = a; ub.s = b;
  return __builtin_amdgcn_mfma_f32_16x16x32_bf16(ua.b, ub.b, c, 0, 0, 0);
}
__device__ __forceinline__ void gll16(const void* g, void* l) {
  __builtin_amdgcn_global_load_lds((__attribute__((address_space(1))) void*)g,
                                   (__attribute__((address_space(3))) void*)l,
                                   16, 0, 0);
}
__device__ __forceinline__ float sigf(float x) { return 1.0f / (1.0f + __expf(-x)); }

// ---------------------------------------------------------------------------
// scores[m] = sum_h tanh( (ctx @ weT^T)[m][h] + qd[b][h] ) * v[h]
// 128m x 256n tile, BK=32, 512 threads (8 waves as 2m x 4n of 64x64).
// A read DIRECTLY from f32 ctx (reg-staged float4 -> v_cvt_pk_bf16_f32 ->
// ds_write_b128); both A and B LDS paths XOR-swizzled (0 conflicts, r11).
// NEW r14: r6-proven counted-vmcnt dual-barrier schedule replaces
// __syncthreads: top wait = vmcnt(2) lgkmcnt(0) (tile t's 2 B-gll16 landed,
// own ds_writes flushed), leaving tile t+1's 2 gll16 in flight across the
// raw s_barrier; stage(t+2) after barrier-2 issues A f32 loads FIRST (cvt
// retires only them), then B gll16. Tail kt=63 drains vmcnt(0).
// XCD-grouped 1-D grid (A panel L2-resident, r7-proven).
// ---------------------------------------------------------------------------
__global__ __launch_bounds__(512, 4) void k_scores_f32(
    const float* __restrict__ ctx, const u16* __restrict__ weT,
    const float* __restrict__ qd, const float* __restrict__ att_v,
    float* __restrict__ scores)
{
  __shared__ u16 As[2][4096];  // [128][32] bf16
  __shared__ u16 Bs[2][8192];  // [256][32] bf16

  const int tid = threadIdx.x;
  const int lane = tid & 63, wid = tid >> 6;  // 8 waves
  const int l15 = lane & 15, lg = lane >> 4;
  const int wm = wid >> 2, wn = wid & 3;      // 2m x 4n

  // XCD-grouped swizzle: f -> (mtile, ntile); 4 n-sharers same XCD
  const int f = blockIdx.x;                   // 2048 blocks
  const int xcd = f & 7, slot = f >> 3;       // slot 0..255
  const int ntile = slot & 3;
  const int mtile = (slot >> 2) * 8 + xcd;    // 0..511
  const int n0 = ntile * 256;
  const int m0 = mtile * 128;
  const int b = mtile >> 1;                   // 128-row tile within one batch row

  // A reg-stage coords: thread owns row tid>>2, f32 cols (tid&3)*8 .. +7
  // LDS write slot XOR-swizzled with (row>>1)&3 (involution with read side)
  const int arow = tid >> 2;
  const float* actx = ctx + (size_t)(m0 + arow) * 2048 + (tid & 3) * 8;
  const int awoff = arow * 32 + (((tid & 3) ^ ((arow >> 1) & 3)) * 8);  // u16 units

  // B gll16 sources with swizzled slot (involution with read side)
  const int sslot = ((lane & 3) ^ ((lane >> 3) & 3)) * 8;  // u16 units
  size_t bsrc[2];
#pragma unroll
  for (int i = 0; i < 2; ++i)
    bsrc[i] = (size_t)(n0 + (wid * 2 + i) * 16 + (lane >> 2)) * 2048 + sslot;

  // read slots: both A and B swizzled with lg ^ ((l15>>1)&3)
  const int rslot = (lg ^ ((l15 >> 1) & 3)) * 8;  // u16 units
  int aoff[4], boff[4];
#pragma unroll
  for (int mf = 0; mf < 4; ++mf) aoff[mf] = (wm * 64 + mf * 16 + l15) * 32 + rslot;
#pragma unroll
  for (int nf = 0; nf < 4; ++nf) boff[nf] = (wn * 64 + nf * 16 + l15) * 32 + rslot;

  f32x4 acc[4][4];
#pragma unroll
  for (int mf = 0; mf < 4; ++mf)
#pragma unroll
    for (int nf = 0; nf < 4; ++nf) acc[mf][nf] = (f32x4){0.f, 0.f, 0.f, 0.f};

  // prologue: stage tiles 0 and 1 into slots 0 and 1
#pragma unroll
  for (int t = 0; t < 2; ++t) {
    float4 a0 = *(const float4*)(actx + (size_t)t * 32);
    float4 a1 = *(const float4*)(actx + (size_t)t * 32 + 4);
#pragma unroll
    for (int i = 0; i < 2; ++i)
      gll16(weT + bsrc[i] + (size_t)t * 32, &Bs[t][(wid * 2 + i) * 512]);
    u32x4 w = {cvt2(a0.x, a0.y), cvt2(a0.z, a0.w), cvt2(a1.x, a1.y), cvt2(a1.z, a1.w)};
    *(u32x4*)&As[t][awoff] = w;
  }

  for (int kt = 0; kt < 64; ++kt) {
    const int cur = kt & 1;
    // tile kt's 2 B-gll16 are the oldest; leave tile kt+1's 2 in flight.
    // lgkmcnt(0): own ds_writes flushed before cross-wave barrier.
    if (kt < 63) asm volatile("s_waitcnt vmcnt(2) lgkmcnt(0)" ::: "memory");
    else         asm volatile("s_waitcnt vmcnt(0) lgkmcnt(0)" ::: "memory");
    __builtin_amdgcn_s_barrier();           // slot-cur data visible to all
    __builtin_amdgcn_sched_barrier(0);
    s16x8 af[4], bf[4];
#pragma unroll
    for (int mf = 0; mf < 4; ++mf) af[mf] = *(const s16x8*)(&As[cur][0] + aoff[mf]);
#pragma unroll
    for (int nf = 0; nf < 4; ++nf) bf[nf] = *(const s16x8*)(&Bs[cur][0] + boff[nf]);
    __builtin_amdgcn_s_setprio(1);
#pragma unroll
    for (int nf = 0; nf < 4; ++nf)
#pragma unroll
      for (int mf = 0; mf < 4; ++mf)
        acc[mf][nf] = mfma_bf16(af[mf], bf[nf], acc[mf][nf]);
    __builtin_amdgcn_s_setprio(0);
    __builtin_amdgcn_s_barrier();           // all waves done reading slot cur
    __builtin_amdgcn_sched_barrier(0);
    if (kt + 2 < 64) {                      // stage tile kt+2 into slot cur
      // A loads FIRST (oldest) so cvt's implicit wait leaves B gll16 in flight
      float4 a0 = *(const float4*)(actx + (size_t)(kt + 2) * 32);
      float4 a1 = *(const float4*)(actx + (size_t)(kt + 2) * 32 + 4);
#pragma unroll
      for (int i = 0; i < 2; ++i)
        gll16(weT + bsrc[i] + (size_t)(kt + 2) * 32, &Bs[cur][(wid * 2 + i) * 512]);
      u32x4 w = {cvt2(a0.x, a0.y), cvt2(a0.z, a0.w), cvt2(a1.x, a1.y), cvt2(a1.z, a1.w)};
      *(u32x4*)&As[cur][awoff] = w;
    }
  }

  // epilogue: rp[row] = sum over this wave's 64 cols of tanh(acc+qd)*v
  float rp[4][4] = {{0.f, 0.f, 0.f, 0.f}, {0.f, 0.f, 0.f, 0.f},
                    {0.f, 0.f, 0.f, 0.f}, {0.f, 0.f, 0.f, 0.f}};
#pragma unroll
  for (int nf = 0; nf < 4; ++nf) {
    int col = n0 + wn * 64 + nf * 16 + l15;
    float qv = qd[(size_t)b * 1024 + col];
    float vv = att_v[col];
#pragma unroll
    for (int mf = 0; mf < 4; ++mf)
#pragma unroll
      for (int e = 0; e < 4; ++e)
        rp[mf][e] += tanhf(acc[mf][nf][e] + qv) * vv;
  }
#pragma unroll
  for (int d = 1; d < 16; d <<= 1)
#pragma unroll
    for (int mf = 0; mf < 4; ++mf)
#pragma unroll
      for (int e = 0; e < 4; ++e)
        rp[mf][e] += __shfl_xor(rp[mf][e], d);
  if (l15 == 0) {
#pragma unroll
    for (int mf = 0; mf < 4; ++mf)
#pragma unroll
      for (int e = 0; e < 4; ++e)
        atomicAdd(&scores[(size_t)m0 + wm * 64 + mf * 16 + lg * 4 + e], rp[mf][e]);
  }
}

// ---------------------------------------------------------------------------
// Generic small GEMM: C[M=256,N] (+)= A(bf16,(256,K)) @ W^T
//   MODE 0: W is (N,K) f32 row-major; MODE 1: W is (K,N) f32 row-major
// Tile: BM=256, BN=64, BK=32. 4 waves, wave tile 64m x 64n. split-K via
// blockIdx.z -> atomicAdd into pre-zeroed C (atomic_mode=1), else store+bias.
// ---------------------------------------------------------------------------
template <int MODE>
__global__ __launch_bounds__(256, 2) void k_gemm(
    const u16* __restrict__ A, const float* __restrict__ W,
    float* __restrict__ C, const float* __restrict__ bias,
    int N, int K, int ksteps_per, int tot_ksteps, int atomic_mode)
{
  __shared__ u16 As[2][8192];  // 256 x 32
  __shared__ u16 Bs[2][2048];  // 64 x 32
  const int tid = threadIdx.x, lane = tid & 63, wid = tid >> 6;
  const int l15 = lane & 15, lg = lane >> 4;
  const int m0 = blockIdx.x * 256;
  const int n0 = blockIdx.y * 64;
  const int kc0 = blockIdx.z * ksteps_per;
  int kcn = tot_ksteps - kc0;
  if (kcn > ksteps_per) kcn = ksteps_per;

  size_t asrc[4];
#pragma unroll
  for (int j = 0; j < 4; ++j)
    asrc[j] = (size_t)(m0 + wid * 64 + j * 16 + (lane >> 2)) * K + (size_t)(lane & 3) * 8;
  int aoff[4], boff[4];
#pragma unroll
  for (int mf = 0; mf < 4; ++mf) aoff[mf] = (wid * 64 + mf * 16 + l15) * 32 + lg * 8;
#pragma unroll
  for (int nf = 0; nf < 4; ++nf) boff[nf] = (nf * 16 + l15) * 32 + lg * 8;

  // B staging coords
  const int b_row = tid >> 2, b_c8 = tid & 3;   // MODE 0
  const int b_kk = tid >> 3, b_c4 = tid & 7;    // MODE 1

  f32x4 acc[4][4];
#pragma unroll
  for (int mf = 0; mf < 4; ++mf)
#pragma unroll
    for (int nf = 0; nf < 4; ++nf) acc[mf][nf] = (f32x4){0.f, 0.f, 0.f, 0.f};

  // prologue stage kt=kc0 into buf 0
  {
#pragma unroll
    for (int j = 0; j < 4; ++j)
      gll16(A + asrc[j] + (size_t)kc0 * 32, &As[0][wid * 2048 + j * 512]);
    if (MODE == 0) {
      const float* p = W + (size_t)(n0 + b_row) * K + (size_t)kc0 * 32 + b_c8 * 8;
      float4 v0 = *(const float4*)p, v1 = *(const float4*)(p + 4);
      u32* w = (u32*)&Bs[0][b_row * 32 + b_c8 * 8];
      w[0] = pack2(v0.x, v0.y); w[1] = pack2(v0.z, v0.w);
      w[2] = pack2(v1.x, v1.y); w[3] = pack2(v1.z, v1.w);
    } else {
      const float* p = W + (size_t)(kc0 * 32 + b_kk) * N + n0 + b_c4 * 4;
      float4 v0 = *(const float4*)p;
      float4 v1 = *(const float4*)(p + 32);
      int r0 = b_c4 * 4, r1 = 32 + b_c4 * 4;
      Bs[0][(r0 + 0) * 32 + b_kk] = f2bf(v0.x);
      Bs[0][(r0 + 1) * 32 + b_kk] = f2bf(v0.y);
      Bs[0][(r0 + 2) * 32 + b_kk] = f2bf(v0.z);
      Bs[0][(r0 + 3) * 32 + b_kk] = f2bf(v0.w);
      Bs[0][(r1 + 0) * 32 + b_kk] = f2bf(v1.x);
      Bs[0][(r1 + 1) * 32 + b_kk] = f2bf(v1.y);
      Bs[0][(r1 + 2) * 32 + b_kk] = f2bf(v1.z);
      Bs[0][(r1 + 3) * 32 + b_kk] = f2bf(v1.w);
    }
  }
  __syncthreads();

  for (int s = 0; s < kcn; ++s) {
    const int cur = s & 1, nxt = cur ^ 1;
    const bool pf = (s + 1 < kcn);
    const int ktn = kc0 + s + 1;
    float4 v0, v1;
    if (pf) {
#pragma unroll
      for (int j = 0; j < 4; ++j)
        gll16(A + asrc[j] + (size_t)ktn * 32, &As[nxt][wid * 2048 + j * 512]);
      if (MODE == 0) {
        const float* p = W + (size_t)(n0 + b_row) * K + (size_t)ktn * 32 + b_c8 * 8;
        v0 = *(const float4*)p; v1 = *(const float4*)(p + 4);
      } else {
        const float* p = W + (size_t)(ktn * 32 + b_kk) * N + n0 + b_c4 * 4;
        v0 = *(const float4*)p;
        v1 = *(const float4*)(p + 32);
      }
    }
    s16x8 af[4], bf[4];
#pragma unroll
    for (int mf = 0; mf < 4; ++mf) af[mf] = *(const s16x8*)(&As[cur][0] + aoff[mf]);
#pragma unroll
    for (int nf = 0; nf < 4; ++nf) bf[nf] = *(const s16x8*)(&Bs[cur][0] + boff[nf]);
#pragma unroll
    for (int nf = 0; nf < 4; ++nf)
#pragma unroll
      for (int mf = 0; mf < 4; ++mf)
        acc[mf][nf] = mfma_bf16(af[mf], bf[nf], acc[mf][nf]);
    if (pf) {
      if (MODE == 0) {
        u32* w = (u32*)&Bs[nxt][b_row * 32 + b_c8 * 8];
        w[0] = pack2(v0.x, v0.y); w[1] = pack2(v0.z, v0.w);
        w[2] = pack2(v1.x, v1.y); w[3] = pack2(v1.z, v1.w);
      } else {
        int r0 = b_c4 * 4, r1 = 32 + b_c4 * 4;
        Bs[nxt][(r0 + 0) * 32 + b_kk] = f2bf(v0.x);
        Bs[nxt][(r0 + 1) * 32 + b_kk] = f2bf(v0.y);
        Bs[nxt][(r0 + 2) * 32 + b_kk] = f2bf(v0.z);
        Bs[nxt][(r0 + 3) * 32 + b_kk] = f2bf(v0.w);
        Bs[nxt][(r1 + 0) * 32 + b_kk] = f2bf(v1.x);
        Bs[nxt][(r1 + 1) * 32 + b_kk] = f2bf(v1.y);
        Bs[nxt][(r1 + 2) * 32 + b_kk] = f2bf(v1.z);
        Bs[nxt][(r1 + 3) * 32 + b_kk] = f2bf(v1.w);
      }
    }
    __syncthreads();
  }

  const size_t Ns = (size_t)N;
#pragma unroll
  for (int mf = 0; mf < 4; ++mf)
#pragma unroll
    for (int nf = 0; nf < 4; ++nf) {
      int col = n0 + nf * 16 + l15;
#pragma unroll
      for (int e = 0; e < 4; ++e) {
        int row = m0 + wid * 64 + mf * 16 + lg * 4 + e;
        float v = acc[mf][nf][e];
        if (atomic_mode) atomicAdd(&C[row * Ns + col], v);
        else C[row * Ns + col] = v + (bias ? bias[col] : 0.0f);
      }
    }
}

// ---------------------------------------------------------------------------
// Merged prep: blocks [0,2048) transpose att_we -> weT bf16;
// [2048,4096) cast h0 -> bf16; [4096,4352) gather embeddings.
// ---------------------------------------------------------------------------
__global__ __launch_bounds__(256) void k_prep(
    const float* __restrict__ we, u16* __restrict__ weT,
    const float* __restrict__ h0, u16* __restrict__ h0_bf,
    const int* __restrict__ ids, const float* __restrict__ emb,
    float* __restrict__ e0, u16* __restrict__ e0b)
{
  __shared__ float t[32][33];
  const int bid = blockIdx.x, tid = threadIdx.x;
  if (bid < 2048) {
    const int n0 = (bid & 31) * 32, k0 = (bid >> 5) * 32;
#pragma unroll
    for (int p = 0; p < 4; ++p) {
      int e = tid + p * 256, r = e >> 5, c = e & 31;
      t[r][c] = we[(size_t)(k0 + r) * 1024 + n0 + c];
    }
    __syncthreads();
#pragma unroll
    for (int p = 0; p < 4; ++p) {
      int e = tid + p * 256, n = e >> 5, k = e & 31;
      weT[(size_t)(n0 + n) * 2048 + k0 + k] = f2bf(t[k][n]);
    }
  } else if (bid < 4096) {
    int i = (bid - 2048) * 256 + tid;
    h0_bf[i] = f2bf(h0[i]);
  } else {
    int b = bid - 4096;
    int id = ids[b];
    for (int i = tid; i < 512; i += 256) {
      float v = emb[(size_t)id * 512 + i];
      e0[(size_t)b * 512 + i] = v;
      e0b[(size_t)b * 512 + i] = f2bf(v);
    }
  }
}

__global__ void k_cast(const float* __restrict__ s, u16* __restrict__ d, int n)
{
  int i = blockIdx.x * 256 + threadIdx.x;
  if (i < n) d[i] = f2bf(s[i]);
}

// ---------------------------------------------------------------------------
// Single-pass softmax over pred rows (32000): row cached as bf16 in LDS,
// online (max,sum) from the ROUNDED values (self-consistent), 1024 threads.
// ---------------------------------------------------------------------------
__global__ __launch_bounds__(1024) void k_softmax_pred(const float* __restrict__ pred,
                                                       u16* __restrict__ probs)
{
  __shared__ u16 xrow[32000];
  __shared__ float smM[16], smS[16];
  const int row = blockIdx.x, tid = threadIdx.x;
  const float* x = pred + (size_t)row * 32000;
  float m = -3.0e38f, s = 0.f;
  for (int i = tid; i < 32000; i += 1024) {
    u16 bv = f2bf(x[i]);
    xrow[i] = bv;
    float vr = bf2f(bv);
    if (vr > m) { s = s * __expf(m - vr) + 1.0f; m = vr; }
    else s += __expf(vr - m);
  }
#pragma unroll
  for (int d = 1; d < 64; d <<= 1) {
    float mo = __shfl_xor(m, d), so = __shfl_xor(s, d);
    float M = fmaxf(m, mo);
    s = s * __expf(m - M) + so * __expf(mo - M);
    m = M;
  }
  if ((tid & 63) == 0) { smM[tid >> 6] = m; smS[tid >> 6] = s; }
  __syncthreads();
  float M = -3.0e38f;
#pragma unroll
  for (int w = 0; w < 16; ++w) M = fmaxf(M, smM[w]);
  float S = 0.f;
#pragma unroll
  for (int w = 0; w < 16; ++w) S += smS[w] * __expf(smM[w] - M);
  float inv = 1.0f / S;
  for (int i = tid; i < 32000; i += 1024)
    probs[(size_t)row * 32000 + i] = f2bf(__expf(bf2f(xrow[i]) - M) * inv);
}

// ---------------------------------------------------------------------------
// Fused scores-softmax + context reduction (f32 ctx). grid (2, 256):
// each block recomputes the 256-wide softmax of its row (trivial), block
// x==0 writes attn out; then each block reduces its 1024-col c_t slice with
// float4 loads (16B/lane coalescing sweet spot, G13).
// ---------------------------------------------------------------------------
__global__ __launch_bounds__(256) void k_attn_ct(
    const float* __restrict__ sc, const float* __restrict__ ctx,
    float* __restrict__ attn, float* __restrict__ c_t)
{
  __shared__ float sm[4];
  __shared__ float att[256];
  const int b = blockIdx.y, tid = threadIdx.x;
  float x = sc[(size_t)b * 256 + tid];
  float mx = x;
#pragma unroll
  for (int d = 1; d < 64; d <<= 1) mx = fmaxf(mx, __shfl_xor(mx, d));
  if ((tid & 63) == 0) sm[tid >> 6] = mx;
  __syncthreads();
  mx = fmaxf(fmaxf(sm[0], sm[1]), fmaxf(sm[2], sm[3]));
  float e = __expf(x - mx);
  float s = e;
#pragma unroll
  for (int d = 1; d < 64; d <<= 1) s += __shfl_xor(s, d);
  __syncthreads();
  if ((tid & 63) == 0) sm[tid >> 6] = s;
  __syncthreads();
  s = sm[0] + sm[1] + sm[2] + sm[3];
  float a = e / s;
  att[tid] = a;
  if (blockIdx.x == 0) attn[(size_t)b * 256 + tid] = a;
  __syncthreads();

  const int d0 = blockIdx.x * 1024 + tid * 4;
  const float4* cp = (const float4*)(ctx + (size_t)b * 524288 + d0);
  float a0 = 0.f, a1 = 0.f, a2 = 0.f, a3 = 0.f;
#pragma unroll 8
  for (int t = 0; t < 256; ++t) {
    float av = att[t];
    float4 v = cp[(size_t)t * 512];
    a0 += av * v.x; a1 += av * v.y; a2 += av * v.z; a3 += av * v.w;
  }
  float4* o = (float4*)(c_t + (size_t)b * 2048 + d0);
  *o = (float4){a0, a1, a2, a3};
}

// ---------------------------------------------------------------------------
// Fused gate + rnn-input concat: for c<512 compute gated embs (and store it
// for later bn0 concat); for c>=512 copy c_t. Writes bf16 rnn input.
// ---------------------------------------------------------------------------
__global__ void k_gate_cat(const float* __restrict__ gepre, const float* __restrict__ b1,
                           const float* __restrict__ b2, const float* __restrict__ e0,
                           const float* __restrict__ ea, float* __restrict__ embs,
                           const float* __restrict__ ct, u16* __restrict__ out)
{
  int i = blockIdx.x * 256 + threadIdx.x;  // 655360
  int m = i / 2560, c = i - m * 2560;
  float v;
  if (c < 512) {
    int idx = m * 512 + c;
    float hg = sigf(gepre[idx] + b1[c] + b2[c]);
    v = hg * e0[idx] + (1.0f - hg) * ea[idx];
    embs[idx] = v;
  } else {
    v = ct[(size_t)m * 2048 + (c - 512)];
  }
  out[i] = f2bf(v);
}

__global__ void k_gru(const float* __restrict__ gi, const float* __restrict__ gh,
                      const float* __restrict__ bih, const float* __restrict__ bhh,
                      const float* __restrict__ hprev, float* __restrict__ hout,
                      u16* __restrict__ hout_bf)
{
  int i = blockIdx.x * 256 + threadIdx.x;  // 262144
  int m = i >> 10, h = i & 1023;
  const float* gim = gi + (size_t)m * 3072;
  const float* ghm = gh + (size_t)m * 3072;
  float r = sigf(gim[h] + bih[h] + ghm[h] + bhh[h]);
  float z = sigf(gim[1024 + h] + bih[1024 + h] + ghm[1024 + h] + bhh[1024 + h]);
  float n = tanhf(gim[2048 + h] + bih[2048 + h] + r * (ghm[2048 + h] + bhh[2048 + h]));
  float hv = (1.0f - z) * n + z * hprev[i];
  hout[i] = hv;
  if (hout_bf) hout_bf[i] = f2bf(hv);
}

__global__ void k_cat_bn0(const float* __restrict__ h11, const float* __restrict__ ct,
                          const float* __restrict__ embs, u16* __restrict__ out)
{
  int i = blockIdx.x * 256 + threadIdx.x;  // 917504
  int m = i / 3584, c = i - m * 3584;
  float v;
  if (c < 1024) v = h11[(size_t)m * 1024 + c];
  else if (c < 3072) v = ct[(size_t)m * 2048 + (c - 1024)];
  else v = embs[(size_t)m * 512 + (c - 3072)];
  out[i] = f2bf(v);
}

__global__ void k_bn0(const float* __restrict__ pre, const float* __restrict__ bias,
                      u16* __restrict__ b0b)
{
  int i = blockIdx.x * 256 + threadIdx.x;  // 131072
  int nn = i & 511;
  b0b[i] = f2bf(tanhf(pre[i] + bias[nn]));
}

__global__ void k_mask(const int* __restrict__ mask, float* __restrict__ pred)
{
  int t = blockIdx.x * 256 + threadIdx.x;  // 2048
  if (t >= 2048) return;
  int b = t >> 3;
  int col = mask[t];
  if (col != 0 && col != 3) pred[(size_t)b * 32000 + col] = -10000000.0f;
}

// ---------------------------------------------------------------------------
// Launch
// ---------------------------------------------------------------------------
extern "C" void kernel_launch(void* const* d_in, const int* in_sizes, int n_in,
                              void* d_out, int out_size, void* d_ws, size_t ws_size,
                              hipStream_t stream)
{
  const int*   input_ids = (const int*)d_in[0];
  const float* prediction= (const float*)d_in[1];
  const float* context   = (const float*)d_in[2];
  const float* h0        = (const float*)d_in[3];
  const int*   maskp     = (const int*)d_in[4];
  const float* embedding = (const float*)d_in[5];
  const float* ge1_w = (const float*)d_in[6];
  const float* ge1_b = (const float*)d_in[7];
  const float* ge2_w = (const float*)d_in[8];
  const float* ge2_b = (const float*)d_in[9];
  const float* att_we = (const float*)d_in[10];
  const float* att_wd = (const float*)d_in[11];
  const float* att_v  = (const float*)d_in[12];
  const float* wih0 = (const float*)d_in[13];
  const float* whh0 = (const float*)d_in[14];
  const float* bih0 = (const float*)d_in[15];
  const float* bhh0 = (const float*)d_in[16];
  const float* wih1 = (const float*)d_in[17];
  const float* whh1 = (const float*)d_in[18];
  const float* bih1 = (const float*)d_in[19];
  const float* bhh1 = (const float*)d_in[20];
  const float* bn0_w = (const float*)d_in[21];
  const float* bn0_b = (const float*)d_in[22];
  const float* bn1_w = (const float*)d_in[23];
  const float* bn1_b = (const float*)d_in[24];

  float* out = (float*)d_out;
  float* out_pred = out;                    // 256*32000
  float* out_h1_0 = out + 8192000;          // 256*1024
  float* out_h1_1 = out + 8454144;          // 256*1024
  float* out_attn = out + 8716288;          // 256*256

  char* ws = (char*)d_ws;
  // memset region (split-K atomic targets + scores)
  float* qd      = (float*)(ws + 0);         // 1048576 B
  float* emb_avg = (float*)(ws + 1048576);   // 524288
  float* gepre   = (float*)(ws + 1572864);   // 524288
  float* gi0     = (float*)(ws + 2097152);   // 3145728
  float* gh0     = (float*)(ws + 5242880);   // 3145728
  float* gi1     = (float*)(ws + 8388608);   // 3145728
  float* gh1     = (float*)(ws + 11534336);  // 3145728
  float* bn0pre  = (float*)(ws + 14680064);  // 524288
  float* scores  = (float*)(ws + 15204352);  // 262144 (atomic target)
  const size_t MS_BYTES = 15466496;
  // non-memset
  float* c_t     = (float*)(ws + 15466496);  // 2097152
  float* embs0   = (float*)(ws + 17563648);  // 524288
  float* embs    = (float*)(ws + 18087936);  // 524288
  u16* weT       = (u16*)(ws + 18612224);    // 4194304
  u16* h0_bf     = (u16*)(ws + 22806528);    // 1048576
  u16* embs0_bf  = (u16*)(ws + 23855104);    // 262144
  u16* probs_bf  = (u16*)(ws + 24117248);    // 16384000
  u16* embavg_bf = (u16*)(ws + 40501248);    // 262144
  u16* rnnin_bf  = (u16*)(ws + 40763392);    // 1310720
  u16* h1_0_bf   = (u16*)(ws + 42074112);    // 524288
  u16* bn0in_bf  = (u16*)(ws + 42598400);    // 1835008
  u16* b0_bf     = (u16*)(ws + 44433408);    // 262144

  (void)in_sizes; (void)n_in; (void)out_size; (void)ws_size;

  hipMemsetAsync(ws, 0, MS_BYTES, stream);

  // prep
  k_prep<<<4352, 256, 0, stream>>>(att_we, weT, h0, h0_bf, input_ids, embedding,
                                   embs0, embs0_bf);
  k_softmax_pred<<<256, 1024, 0, stream>>>(prediction, probs_bf);

  // qd = h0[1] @ att_wd   (MODE1, atomic split-K x8)
  k_gemm<1><<<dim3(1, 16, 8), 256, 0, stream>>>(h0_bf + 262144, att_wd, qd, nullptr,
                                                1024, 1024, 4, 32, 1);
  // big fused attention-scores kernel (f32 A read directly, no cvt pass)
  k_scores_f32<<<2048, 512, 0, stream>>>(context, weT, qd, att_v, scores);

  // emb_avg = probs @ embedding (MODE1, split-K x50)
  k_gemm<1><<<dim3(1, 8, 50), 256, 0, stream>>>(probs_bf, embedding, emb_avg, nullptr,
                                                512, 32000, 20, 1000, 1);
  k_cast<<<512, 256, 0, stream>>>(emb_avg, embavg_bf, 131072);
  // gepre = embs0@ge1_w + emb_avg@ge2_w
  k_gemm<1><<<dim3(1, 8, 4), 256, 0, stream>>>(embs0_bf, ge1_w, gepre, nullptr,
                                               512, 512, 4, 16, 1);
  k_gemm<1><<<dim3(1, 8, 4), 256, 0, stream>>>(embavg_bf, ge2_w, gepre, nullptr,
                                               512, 512, 4, 16, 1);

  // attention softmax + context reduction (f32 ctx, float4 loads)
  k_attn_ct<<<dim3(2, 256), 256, 0, stream>>>(scores, context, out_attn, c_t);

  // gate + rnn-input concat (fused)
  k_gate_cat<<<2560, 256, 0, stream>>>(gepre, ge1_b, ge2_b, embs0, emb_avg,
                                       embs, c_t, rnnin_bf);

  // GRU layer 0
  k_gemm<0><<<dim3(1, 48, 5), 256, 0, stream>>>(rnnin_bf, wih0, gi0, nullptr,
                                                3072, 2560, 16, 80, 1);
  k_gemm<0><<<dim3(1, 48, 4), 256, 0, stream>>>(h0_bf, whh0, gh0, nullptr,
                                                3072, 1024, 8, 32, 1);
  k_gru<<<1024, 256, 0, stream>>>(gi0, gh0, bih0, bhh0, h0, out_h1_0, h1_0_bf);
  // GRU layer 1
  k_gemm<0><<<dim3(1, 48, 4), 256, 0, stream>>>(h1_0_bf, wih1, gi1, nullptr,
                                                3072, 1024, 8, 32, 1);
  k_gemm<0><<<dim3(1, 48, 4), 256, 0, stream>>>(h0_bf + 262144, whh1, gh1, nullptr,
                                                3072, 1024, 8, 32, 1);
  k_gru<<<1024, 256, 0, stream>>>(gi1, gh1, bih1, bhh1, h0 + 262144, out_h1_1, nullptr);

  // bottleneck + output projection
  k_cat_bn0<<<3584, 256, 0, stream>>>(out_h1_1, c_t, embs, bn0in_bf);
  k_gemm<1><<<dim3(1, 8, 16), 256, 0, stream>>>(bn0in_bf, bn0_w, bn0pre, nullptr,
                                                512, 3584, 7, 112, 1);
  k_bn0<<<512, 256, 0, stream>>>(bn0pre, bn0_b, b0_bf);
  k_gemm<1><<<dim3(1, 500, 1), 256, 0, stream>>>(b0_bf, bn1_w, out_pred, bn1_b,
                                                 32000, 512, 16, 16, 0);
  k_mask<<<8, 256, 0, stream>>>(maskp, out_pred);
}

// Round 15
// 773.707 us; speedup vs baseline: 1.0234x; 1.0234x over previous
//
#include <hip/hip_runtime.h>
#include <hip/hip_bf16.h>

// ---------------------------------------------------------------------------
// rnn_decoder: B=256 T=256 H=1024 E=512 V=32000 BN=512
// out = [pred (256x32000) | h1 (2x256x1024) | attn (256x256)]  (f32)
// All GEMMs bf16 MFMA (16x16x32), consistent assumed k-mapping for A and B
// fragments => correctness independent of HW internal K ordering. C layout:
// col=lane&15, row=(lane>>4)*4+reg (HW-verified m89).
// This is the r13 configuration (774.6us, session best) restored after the
// r14 counted-vmcnt experiment regressed (-3.5% on k_scores; 4th null/neg
// schedule-lever result on this template -> practical plateau).
// ---------------------------------------------------------------------------

typedef unsigned short u16;
typedef unsigned int u32;
typedef float f32x4 __attribute__((ext_vector_type(4)));
typedef u32 u32x4 __attribute__((ext_vector_type(4)));
typedef __bf16 bf16x8 __attribute__((ext_vector_type(8)));
typedef short s16x8 __attribute__((ext_vector_type(8)));

__device__ __forceinline__ u16 f2bf(float x) {
  u32 u = __float_as_uint(x);
  u += 0x7fffu + ((u >> 16) & 1u);
  return (u16)(u >> 16);
}
__device__ __forceinline__ u32 pack2(float a, float b) {
  return (u32)f2bf(a) | ((u32)f2bf(b) << 16);
}
// HW RTNE f32->bf16 pair (compiler emits v_cvt_pk_bf16_f32)
__device__ __forceinline__ u32 cvt2(float a, float b) {
  union { __bf16 h[2]; u32 w; } u;
  u.h[0] = (__bf16)a; u.h[1] = (__bf16)b;
  return u.w;
}
__device__ __forceinline__ float bf2f(u16 v) {
  return __uint_as_float((u32)v << 16);
}
__device__ __forceinline__ f32x4 mfma_bf16(s16x8 a, s16x8 b, f32x4 c) {
  union { s16x8 s; bf16x8 b; } ua, ub;
  ua.s = a; ub.s = b;
  return __builtin_amdgcn_mfma_f32_16x16x32_bf16(ua.b, ub.b, c, 0, 0, 0);
}
__device__ __forceinline__ void gll16(const void* g, void* l) {
  __builtin_amdgcn_global_load_lds((__attribute__((address_space(1))) void*)g,
                                   (__attribute__((address_space(3))) void*)l,
                                   16, 0, 0);
}
__device__ __forceinline__ float sigf(float x) { return 1.0f / (1.0f + __expf(-x)); }

// ---------------------------------------------------------------------------
// scores[m] = sum_h tanh( (ctx @ weT^T)[m][h] + qd[b][h] ) * v[h]
// 128m x 256n tile, BK=32, 512 threads (8 waves as 2m x 4n of 64x64).
// A read DIRECTLY from f32 ctx (reg-staged float4 -> v_cvt_pk_bf16_f32 ->
// ds_write_b128); both A and B LDS paths XOR-swizzled (0 bank conflicts,
// verified r11). B staged via global_load_lds with pre-swizzled source.
// Double-buffer + __syncthreads. XCD-grouped 1-D grid (A panel L2-resident).
// ---------------------------------------------------------------------------
__global__ __launch_bounds__(512, 4) void k_scores_f32(
    const float* __restrict__ ctx, const u16* __restrict__ weT,
    const float* __restrict__ qd, const float* __restrict__ att_v,
    float* __restrict__ scores)
{
  __shared__ u16 As[2][4096];  // [128][32] bf16
  __shared__ u16 Bs[2][8192];  // [256][32] bf16

  const int tid = threadIdx.x;
  const int lane = tid & 63, wid = tid >> 6;  // 8 waves
  const int l15 = lane & 15, lg = lane >> 4;
  const int wm = wid >> 2, wn = wid & 3;      // 2m x 4n

  // XCD-grouped swizzle: f -> (mtile, ntile); 4 n-sharers same XCD
  const int f = blockIdx.x;                   // 2048 blocks
  const int xcd = f & 7, slot = f >> 3;       // slot 0..255
  const int ntile = slot & 3;
  const int mtile = (slot >> 2) * 8 + xcd;    // 0..511
  const int n0 = ntile * 256;
  const int m0 = mtile * 128;
  const int b = mtile >> 1;                   // 128-row tile within one batch row

  // A reg-stage coords: thread owns row tid>>2, f32 cols (tid&3)*8 .. +7
  // LDS write slot XOR-swizzled with (row>>1)&3 (involution with read side)
  const int arow = tid >> 2;
  const float* actx = ctx + (size_t)(m0 + arow) * 2048 + (tid & 3) * 8;
  const int awoff = arow * 32 + (((tid & 3) ^ ((arow >> 1) & 3)) * 8);  // u16 units

  // B gll16 sources with swizzled slot (involution with read side)
  const int sslot = ((lane & 3) ^ ((lane >> 3) & 3)) * 8;  // u16 units
  size_t bsrc[2];
#pragma unroll
  for (int i = 0; i < 2; ++i)
    bsrc[i] = (size_t)(n0 + (wid * 2 + i) * 16 + (lane >> 2)) * 2048 + sslot;

  // read slots: both A and B swizzled with lg ^ ((l15>>1)&3)
  const int rslot = (lg ^ ((l15 >> 1) & 3)) * 8;  // u16 units
  int aoff[4], boff[4];
#pragma unroll
  for (int mf = 0; mf < 4; ++mf) aoff[mf] = (wm * 64 + mf * 16 + l15) * 32 + rslot;
#pragma unroll
  for (int nf = 0; nf < 4; ++nf) boff[nf] = (wn * 64 + nf * 16 + l15) * 32 + rslot;

  f32x4 acc[4][4];
#pragma unroll
  for (int mf = 0; mf < 4; ++mf)
#pragma unroll
    for (int nf = 0; nf < 4; ++nf) acc[mf][nf] = (f32x4){0.f, 0.f, 0.f, 0.f};

  // prologue: stage kt=0 into buf 0
  {
#pragma unroll
    for (int i = 0; i < 2; ++i)
      gll16(weT + bsrc[i], &Bs[0][(wid * 2 + i) * 512]);
    float4 a0 = *(const float4*)(actx);
    float4 a1 = *(const float4*)(actx + 4);
    u32x4 w = {cvt2(a0.x, a0.y), cvt2(a0.z, a0.w), cvt2(a1.x, a1.y), cvt2(a1.z, a1.w)};
    *(u32x4*)&As[0][awoff] = w;
  }
  __syncthreads();

  for (int kt = 0; kt < 64; ++kt) {
    const int cur = kt & 1, nxt = cur ^ 1;
    const bool pf = (kt < 63);
    float4 a0, a1;
    if (pf) {
#pragma unroll
      for (int i = 0; i < 2; ++i)
        gll16(weT + bsrc[i] + (size_t)(kt + 1) * 32, &Bs[nxt][(wid * 2 + i) * 512]);
      a0 = *(const float4*)(actx + (size_t)(kt + 1) * 32);
      a1 = *(const float4*)(actx + (size_t)(kt + 1) * 32 + 4);
    }
    s16x8 af[4], bf[4];
#pragma unroll
    for (int mf = 0; mf < 4; ++mf) af[mf] = *(const s16x8*)(&As[cur][0] + aoff[mf]);
#pragma unroll
    for (int nf = 0; nf < 4; ++nf) bf[nf] = *(const s16x8*)(&Bs[cur][0] + boff[nf]);
    __builtin_amdgcn_s_setprio(1);
#pragma unroll
    for (int nf = 0; nf < 4; ++nf)
#pragma unroll
      for (int mf = 0; mf < 4; ++mf)
        acc[mf][nf] = mfma_bf16(af[mf], bf[nf], acc[mf][nf]);
    __builtin_amdgcn_s_setprio(0);
    if (pf) {
      u32x4 w = {cvt2(a0.x, a0.y), cvt2(a0.z, a0.w), cvt2(a1.x, a1.y), cvt2(a1.z, a1.w)};
      *(u32x4*)&As[nxt][awoff] = w;
    }
    __syncthreads();
  }

  // epilogue: rp[row] = sum over this wave's 64 cols of tanh(acc+qd)*v
  float rp[4][4] = {{0.f, 0.f, 0.f, 0.f}, {0.f, 0.f, 0.f, 0.f},
                    {0.f, 0.f, 0.f, 0.f}, {0.f, 0.f, 0.f, 0.f}};
#pragma unroll
  for (int nf = 0; nf < 4; ++nf) {
    int col = n0 + wn * 64 + nf * 16 + l15;
    float qv = qd[(size_t)b * 1024 + col];
    float vv = att_v[col];
#pragma unroll
    for (int mf = 0; mf < 4; ++mf)
#pragma unroll
      for (int e = 0; e < 4; ++e)
        rp[mf][e] += tanhf(acc[mf][nf][e] + qv) * vv;
  }
#pragma unroll
  for (int d = 1; d < 16; d <<= 1)
#pragma unroll
    for (int mf = 0; mf < 4; ++mf)
#pragma unroll
      for (int e = 0; e < 4; ++e)
        rp[mf][e] += __shfl_xor(rp[mf][e], d);
  if (l15 == 0) {
#pragma unroll
    for (int mf = 0; mf < 4; ++mf)
#pragma unroll
      for (int e = 0; e < 4; ++e)
        atomicAdd(&scores[(size_t)m0 + wm * 64 + mf * 16 + lg * 4 + e], rp[mf][e]);
  }
}

// ---------------------------------------------------------------------------
// Generic small GEMM: C[M=256,N] (+)= A(bf16,(256,K)) @ W^T
//   MODE 0: W is (N,K) f32 row-major; MODE 1: W is (K,N) f32 row-major
// Tile: BM=256, BN=64, BK=32. 4 waves, wave tile 64m x 64n. split-K via
// blockIdx.z -> atomicAdd into pre-zeroed C (atomic_mode=1), else store+bias.
// ---------------------------------------------------------------------------
template <int MODE>
__global__ __launch_bounds__(256, 2) void k_gemm(
    const u16* __restrict__ A, const float* __restrict__ W,
    float* __restrict__ C, const float* __restrict__ bias,
    int N, int K, int ksteps_per, int tot_ksteps, int atomic_mode)
{
  __shared__ u16 As[2][8192];  // 256 x 32
  __shared__ u16 Bs[2][2048];  // 64 x 32
  const int tid = threadIdx.x, lane = tid & 63, wid = tid >> 6;
  const int l15 = lane & 15, lg = lane >> 4;
  const int m0 = blockIdx.x * 256;
  const int n0 = blockIdx.y * 64;
  const int kc0 = blockIdx.z * ksteps_per;
  int kcn = tot_ksteps - kc0;
  if (kcn > ksteps_per) kcn = ksteps_per;

  size_t asrc[4];
#pragma unroll
  for (int j = 0; j < 4; ++j)
    asrc[j] = (size_t)(m0 + wid * 64 + j * 16 + (lane >> 2)) * K + (size_t)(lane & 3) * 8;
  int aoff[4], boff[4];
#pragma unroll
  for (int mf = 0; mf < 4; ++mf) aoff[mf] = (wid * 64 + mf * 16 + l15) * 32 + lg * 8;
#pragma unroll
  for (int nf = 0; nf < 4; ++nf) boff[nf] = (nf * 16 + l15) * 32 + lg * 8;

  // B staging coords
  const int b_row = tid >> 2, b_c8 = tid & 3;   // MODE 0
  const int b_kk = tid >> 3, b_c4 = tid & 7;    // MODE 1

  f32x4 acc[4][4];
#pragma unroll
  for (int mf = 0; mf < 4; ++mf)
#pragma unroll
    for (int nf = 0; nf < 4; ++nf) acc[mf][nf] = (f32x4){0.f, 0.f, 0.f, 0.f};

  // prologue stage kt=kc0 into buf 0
  {
#pragma unroll
    for (int j = 0; j < 4; ++j)
      gll16(A + asrc[j] + (size_t)kc0 * 32, &As[0][wid * 2048 + j * 512]);
    if (MODE == 0) {
      const float* p = W + (size_t)(n0 + b_row) * K + (size_t)kc0 * 32 + b_c8 * 8;
      float4 v0 = *(const float4*)p, v1 = *(const float4*)(p + 4);
      u32* w = (u32*)&Bs[0][b_row * 32 + b_c8 * 8];
      w[0] = pack2(v0.x, v0.y); w[1] = pack2(v0.z, v0.w);
      w[2] = pack2(v1.x, v1.y); w[3] = pack2(v1.z, v1.w);
    } else {
      const float* p = W + (size_t)(kc0 * 32 + b_kk) * N + n0 + b_c4 * 4;
      float4 v0 = *(const float4*)p;
      float4 v1 = *(const float4*)(p + 32);
      int r0 = b_c4 * 4, r1 = 32 + b_c4 * 4;
      Bs[0][(r0 + 0) * 32 + b_kk] = f2bf(v0.x);
      Bs[0][(r0 + 1) * 32 + b_kk] = f2bf(v0.y);
      Bs[0][(r0 + 2) * 32 + b_kk] = f2bf(v0.z);
      Bs[0][(r0 + 3) * 32 + b_kk] = f2bf(v0.w);
      Bs[0][(r1 + 0) * 32 + b_kk] = f2bf(v1.x);
      Bs[0][(r1 + 1) * 32 + b_kk] = f2bf(v1.y);
      Bs[0][(r1 + 2) * 32 + b_kk] = f2bf(v1.z);
      Bs[0][(r1 + 3) * 32 + b_kk] = f2bf(v1.w);
    }
  }
  __syncthreads();

  for (int s = 0; s < kcn; ++s) {
    const int cur = s & 1, nxt = cur ^ 1;
    const bool pf = (s + 1 < kcn);
    const int ktn = kc0 + s + 1;
    float4 v0, v1;
    if (pf) {
#pragma unroll
      for (int j = 0; j < 4; ++j)
        gll16(A + asrc[j] + (size_t)ktn * 32, &As[nxt][wid * 2048 + j * 512]);
      if (MODE == 0) {
        const float* p = W + (size_t)(n0 + b_row) * K + (size_t)ktn * 32 + b_c8 * 8;
        v0 = *(const float4*)p; v1 = *(const float4*)(p + 4);
      } else {
        const float* p = W + (size_t)(ktn * 32 + b_kk) * N + n0 + b_c4 * 4;
        v0 = *(const float4*)p;
        v1 = *(const float4*)(p + 32);
      }
    }
    s16x8 af[4], bf[4];
#pragma unroll
    for (int mf = 0; mf < 4; ++mf) af[mf] = *(const s16x8*)(&As[cur][0] + aoff[mf]);
#pragma unroll
    for (int nf = 0; nf < 4; ++nf) bf[nf] = *(const s16x8*)(&Bs[cur][0] + boff[nf]);
#pragma unroll
    for (int nf = 0; nf < 4; ++nf)
#pragma unroll
      for (int mf = 0; mf < 4; ++mf)
        acc[mf][nf] = mfma_bf16(af[mf], bf[nf], acc[mf][nf]);
    if (pf) {
      if (MODE == 0) {
        u32* w = (u32*)&Bs[nxt][b_row * 32 + b_c8 * 8];
        w[0] = pack2(v0.x, v0.y); w[1] = pack2(v0.z, v0.w);
        w[2] = pack2(v1.x, v1.y); w[3] = pack2(v1.z, v1.w);
      } else {
        int r0 = b_c4 * 4, r1 = 32 + b_c4 * 4;
        Bs[nxt][(r0 + 0) * 32 + b_kk] = f2bf(v0.x);
        Bs[nxt][(r0 + 1) * 32 + b_kk] = f2bf(v0.y);
        Bs[nxt][(r0 + 2) * 32 + b_kk] = f2bf(v0.z);
        Bs[nxt][(r0 + 3) * 32 + b_kk] = f2bf(v0.w);
        Bs[nxt][(r1 + 0) * 32 + b_kk] = f2bf(v1.x);
        Bs[nxt][(r1 + 1) * 32 + b_kk] = f2bf(v1.y);
        Bs[nxt][(r1 + 2) * 32 + b_kk] = f2bf(v1.z);
        Bs[nxt][(r1 + 3) * 32 + b_kk] = f2bf(v1.w);
      }
    }
    __syncthreads();
  }

  const size_t Ns = (size_t)N;
#pragma unroll
  for (int mf = 0; mf < 4; ++mf)
#pragma unroll
    for (int nf = 0; nf < 4; ++nf) {
      int col = n0 + nf * 16 + l15;
#pragma unroll
      for (int e = 0; e < 4; ++e) {
        int row = m0 + wid * 64 + mf * 16 + lg * 4 + e;
        float v = acc[mf][nf][e];
        if (atomic_mode) atomicAdd(&C[row * Ns + col], v);
        else C[row * Ns + col] = v + (bias ? bias[col] : 0.0f);
      }
    }
}

// ---------------------------------------------------------------------------
// Merged prep: blocks [0,2048) transpose att_we -> weT bf16;
// [2048,4096) cast h0 -> bf16; [4096,4352) gather embeddings.
// ---------------------------------------------------------------------------
__global__ __launch_bounds__(256) void k_prep(
    const float* __restrict__ we, u16* __restrict__ weT,
    const float* __restrict__ h0, u16* __restrict__ h0_bf,
    const int* __restrict__ ids, const float* __restrict__ emb,
    float* __restrict__ e0, u16* __restrict__ e0b)
{
  __shared__ float t[32][33];
  const int bid = blockIdx.x, tid = threadIdx.x;
  if (bid < 2048) {
    const int n0 = (bid & 31) * 32, k0 = (bid >> 5) * 32;
#pragma unroll
    for (int p = 0; p < 4; ++p) {
      int e = tid + p * 256, r = e >> 5, c = e & 31;
      t[r][c] = we[(size_t)(k0 + r) * 1024 + n0 + c];
    }
    __syncthreads();
#pragma unroll
    for (int p = 0; p < 4; ++p) {
      int e = tid + p * 256, n = e >> 5, k = e & 31;
      weT[(size_t)(n0 + n) * 2048 + k0 + k] = f2bf(t[k][n]);
    }
  } else if (bid < 4096) {
    int i = (bid - 2048) * 256 + tid;
    h0_bf[i] = f2bf(h0[i]);
  } else {
    int b = bid - 4096;
    int id = ids[b];
    for (int i = tid; i < 512; i += 256) {
      float v = emb[(size_t)id * 512 + i];
      e0[(size_t)b * 512 + i] = v;
      e0b[(size_t)b * 512 + i] = f2bf(v);
    }
  }
}

__global__ void k_cast(const float* __restrict__ s, u16* __restrict__ d, int n)
{
  int i = blockIdx.x * 256 + threadIdx.x;
  if (i < n) d[i] = f2bf(s[i]);
}

// ---------------------------------------------------------------------------
// Single-pass softmax over pred rows (32000): row cached as bf16 in LDS,
// online (max,sum) from the ROUNDED values (self-consistent), 1024 threads.
// ---------------------------------------------------------------------------
__global__ __launch_bounds__(1024) void k_softmax_pred(const float* __restrict__ pred,
                                                       u16* __restrict__ probs)
{
  __shared__ u16 xrow[32000];
  __shared__ float smM[16], smS[16];
  const int row = blockIdx.x, tid = threadIdx.x;
  const float* x = pred + (size_t)row * 32000;
  float m = -3.0e38f, s = 0.f;
  for (int i = tid; i < 32000; i += 1024) {
    u16 bv = f2bf(x[i]);
    xrow[i] = bv;
    float vr = bf2f(bv);
    if (vr > m) { s = s * __expf(m - vr) + 1.0f; m = vr; }
    else s += __expf(vr - m);
  }
#pragma unroll
  for (int d = 1; d < 64; d <<= 1) {
    float mo = __shfl_xor(m, d), so = __shfl_xor(s, d);
    float M = fmaxf(m, mo);
    s = s * __expf(m - M) + so * __expf(mo - M);
    m = M;
  }
  if ((tid & 63) == 0) { smM[tid >> 6] = m; smS[tid >> 6] = s; }
  __syncthreads();
  float M = -3.0e38f;
#pragma unroll
  for (int w = 0; w < 16; ++w) M = fmaxf(M, smM[w]);
  float S = 0.f;
#pragma unroll
  for (int w = 0; w < 16; ++w) S += smS[w] * __expf(smM[w] - M);
  float inv = 1.0f / S;
  for (int i = tid; i < 32000; i += 1024)
    probs[(size_t)row * 32000 + i] = f2bf(__expf(bf2f(xrow[i]) - M) * inv);
}

// ---------------------------------------------------------------------------
// Fused scores-softmax + context reduction (f32 ctx). grid (2, 256):
// each block recomputes the 256-wide softmax of its row (trivial), block
// x==0 writes attn out; then each block reduces its 1024-col c_t slice with
// float4 loads (16B/lane coalescing sweet spot, G13).
// ---------------------------------------------------------------------------
__global__ __launch_bounds__(256) void k_attn_ct(
    const float* __restrict__ sc, const float* __restrict__ ctx,
    float* __restrict__ attn, float* __restrict__ c_t)
{
  __shared__ float sm[4];
  __shared__ float att[256];
  const int b = blockIdx.y, tid = threadIdx.x;
  float x = sc[(size_t)b * 256 + tid];
  float mx = x;
#pragma unroll
  for (int d = 1; d < 64; d <<= 1) mx = fmaxf(mx, __shfl_xor(mx, d));
  if ((tid & 63) == 0) sm[tid >> 6] = mx;
  __syncthreads();
  mx = fmaxf(fmaxf(sm[0], sm[1]), fmaxf(sm[2], sm[3]));
  float e = __expf(x - mx);
  float s = e;
#pragma unroll
  for (int d = 1; d < 64; d <<= 1) s += __shfl_xor(s, d);
  __syncthreads();
  if ((tid & 63) == 0) sm[tid >> 6] = s;
  __syncthreads();
  s = sm[0] + sm[1] + sm[2] + sm[3];
  float a = e / s;
  att[tid] = a;
  if (blockIdx.x == 0) attn[(size_t)b * 256 + tid] = a;
  __syncthreads();

  const int d0 = blockIdx.x * 1024 + tid * 4;
  const float4* cp = (const float4*)(ctx + (size_t)b * 524288 + d0);
  float a0 = 0.f, a1 = 0.f, a2 = 0.f, a3 = 0.f;
#pragma unroll 8
  for (int t = 0; t < 256; ++t) {
    float av = att[t];
    float4 v = cp[(size_t)t * 512];
    a0 += av * v.x; a1 += av * v.y; a2 += av * v.z; a3 += av * v.w;
  }
  float4* o = (float4*)(c_t + (size_t)b * 2048 + d0);
  *o = (float4){a0, a1, a2, a3};
}

// ---------------------------------------------------------------------------
// Fused gate + rnn-input concat: for c<512 compute gated embs (and store it
// for later bn0 concat); for c>=512 copy c_t. Writes bf16 rnn input.
// ---------------------------------------------------------------------------
__global__ void k_gate_cat(const float* __restrict__ gepre, const float* __restrict__ b1,
                           const float* __restrict__ b2, const float* __restrict__ e0,
                           const float* __restrict__ ea, float* __restrict__ embs,
                           const float* __restrict__ ct, u16* __restrict__ out)
{
  int i = blockIdx.x * 256 + threadIdx.x;  // 655360
  int m = i / 2560, c = i - m * 2560;
  float v;
  if (c < 512) {
    int idx = m * 512 + c;
    float hg = sigf(gepre[idx] + b1[c] + b2[c]);
    v = hg * e0[idx] + (1.0f - hg) * ea[idx];
    embs[idx] = v;
  } else {
    v = ct[(size_t)m * 2048 + (c - 512)];
  }
  out[i] = f2bf(v);
}

__global__ void k_gru(const float* __restrict__ gi, const float* __restrict__ gh,
                      const float* __restrict__ bih, const float* __restrict__ bhh,
                      const float* __restrict__ hprev, float* __restrict__ hout,
                      u16* __restrict__ hout_bf)
{
  int i = blockIdx.x * 256 + threadIdx.x;  // 262144
  int m = i >> 10, h = i & 1023;
  const float* gim = gi + (size_t)m * 3072;
  const float* ghm = gh + (size_t)m * 3072;
  float r = sigf(gim[h] + bih[h] + ghm[h] + bhh[h]);
  float z = sigf(gim[1024 + h] + bih[1024 + h] + ghm[1024 + h] + bhh[1024 + h]);
  float n = tanhf(gim[2048 + h] + bih[2048 + h] + r * (ghm[2048 + h] + bhh[2048 + h]));
  float hv = (1.0f - z) * n + z * hprev[i];
  hout[i] = hv;
  if (hout_bf) hout_bf[i] = f2bf(hv);
}

__global__ void k_cat_bn0(const float* __restrict__ h11, const float* __restrict__ ct,
                          const float* __restrict__ embs, u16* __restrict__ out)
{
  int i = blockIdx.x * 256 + threadIdx.x;  // 917504
  int m = i / 3584, c = i - m * 3584;
  float v;
  if (c < 1024) v = h11[(size_t)m * 1024 + c];
  else if (c < 3072) v = ct[(size_t)m * 2048 + (c - 1024)];
  else v = embs[(size_t)m * 512 + (c - 3072)];
  out[i] = f2bf(v);
}

__global__ void k_bn0(const float* __restrict__ pre, const float* __restrict__ bias,
                      u16* __restrict__ b0b)
{
  int i = blockIdx.x * 256 + threadIdx.x;  // 131072
  int nn = i & 511;
  b0b[i] = f2bf(tanhf(pre[i] + bias[nn]));
}

__global__ void k_mask(const int* __restrict__ mask, float* __restrict__ pred)
{
  int t = blockIdx.x * 256 + threadIdx.x;  // 2048
  if (t >= 2048) return;
  int b = t >> 3;
  int col = mask[t];
  if (col != 0 && col != 3) pred[(size_t)b * 32000 + col] = -10000000.0f;
}

// ---------------------------------------------------------------------------
// Launch
// ---------------------------------------------------------------------------
extern "C" void kernel_launch(void* const* d_in, const int* in_sizes, int n_in,
                              void* d_out, int out_size, void* d_ws, size_t ws_size,
                              hipStream_t stream)
{
  const int*   input_ids = (const int*)d_in[0];
  const float* prediction= (const float*)d_in[1];
  const float* context   = (const float*)d_in[2];
  const float* h0        = (const float*)d_in[3];
  const int*   maskp     = (const int*)d_in[4];
  const float* embedding = (const float*)d_in[5];
  const float* ge1_w = (const float*)d_in[6];
  const float* ge1_b = (const float*)d_in[7];
  const float* ge2_w = (const float*)d_in[8];
  const float* ge2_b = (const float*)d_in[9];
  const float* att_we = (const float*)d_in[10];
  const float* att_wd = (const float*)d_in[11];
  const float* att_v  = (const float*)d_in[12];
  const float* wih0 = (const float*)d_in[13];
  const float* whh0 = (const float*)d_in[14];
  const float* bih0 = (const float*)d_in[15];
  const float* bhh0 = (const float*)d_in[16];
  const float* wih1 = (const float*)d_in[17];
  const float* whh1 = (const float*)d_in[18];
  const float* bih1 = (const float*)d_in[19];
  const float* bhh1 = (const float*)d_in[20];
  const float* bn0_w = (const float*)d_in[21];
  const float* bn0_b = (const float*)d_in[22];
  const float* bn1_w = (const float*)d_in[23];
  const float* bn1_b = (const float*)d_in[24];

  float* out = (float*)d_out;
  float* out_pred = out;                    // 256*32000
  float* out_h1_0 = out + 8192000;          // 256*1024
  float* out_h1_1 = out + 8454144;          // 256*1024
  float* out_attn = out + 8716288;          // 256*256

  char* ws = (char*)d_ws;
  // memset region (split-K atomic targets + scores)
  float* qd      = (float*)(ws + 0);         // 1048576 B
  float* emb_avg = (float*)(ws + 1048576);   // 524288
  float* gepre   = (float*)(ws + 1572864);   // 524288
  float* gi0     = (float*)(ws + 2097152);   // 3145728
  float* gh0     = (float*)(ws + 5242880);   // 3145728
  float* gi1     = (float*)(ws + 8388608);   // 3145728
  float* gh1     = (float*)(ws + 11534336);  // 3145728
  float* bn0pre  = (float*)(ws + 14680064);  // 524288
  float* scores  = (float*)(ws + 15204352);  // 262144 (atomic target)
  const size_t MS_BYTES = 15466496;
  // non-memset
  float* c_t     = (float*)(ws + 15466496);  // 2097152
  float* embs0   = (float*)(ws + 17563648);  // 524288
  float* embs    = (float*)(ws + 18087936);  // 524288
  u16* weT       = (u16*)(ws + 18612224);    // 4194304
  u16* h0_bf     = (u16*)(ws + 22806528);    // 1048576
  u16* embs0_bf  = (u16*)(ws + 23855104);    // 262144
  u16* probs_bf  = (u16*)(ws + 24117248);    // 16384000
  u16* embavg_bf = (u16*)(ws + 40501248);    // 262144
  u16* rnnin_bf  = (u16*)(ws + 40763392);    // 1310720
  u16* h1_0_bf   = (u16*)(ws + 42074112);    // 524288
  u16* bn0in_bf  = (u16*)(ws + 42598400);    // 1835008
  u16* b0_bf     = (u16*)(ws + 44433408);    // 262144

  (void)in_sizes; (void)n_in; (void)out_size; (void)ws_size;

  hipMemsetAsync(ws, 0, MS_BYTES, stream);

  // prep
  k_prep<<<4352, 256, 0, stream>>>(att_we, weT, h0, h0_bf, input_ids, embedding,
                                   embs0, embs0_bf);
  k_softmax_pred<<<256, 1024, 0, stream>>>(prediction, probs_bf);

  // qd = h0[1] @ att_wd   (MODE1, atomic split-K x8)
  k_gemm<1><<<dim3(1, 16, 8), 256, 0, stream>>>(h0_bf + 262144, att_wd, qd, nullptr,
                                                1024, 1024, 4, 32, 1);
  // big fused attention-scores kernel (f32 A read directly, no cvt pass)
  k_scores_f32<<<2048, 512, 0, stream>>>(context, weT, qd, att_v, scores);

  // emb_avg = probs @ embedding (MODE1, split-K x50)
  k_gemm<1><<<dim3(1, 8, 50), 256, 0, stream>>>(probs_bf, embedding, emb_avg, nullptr,
                                                512, 32000, 20, 1000, 1);
  k_cast<<<512, 256, 0, stream>>>(emb_avg, embavg_bf, 131072);
  // gepre = embs0@ge1_w + emb_avg@ge2_w
  k_gemm<1><<<dim3(1, 8, 4), 256, 0, stream>>>(embs0_bf, ge1_w, gepre, nullptr,
                                               512, 512, 4, 16, 1);
  k_gemm<1><<<dim3(1, 8, 4), 256, 0, stream>>>(embavg_bf, ge2_w, gepre, nullptr,
                                               512, 512, 4, 16, 1);

  // attention softmax + context reduction (f32 ctx, float4 loads)
  k_attn_ct<<<dim3(2, 256), 256, 0, stream>>>(scores, context, out_attn, c_t);

  // gate + rnn-input concat (fused)
  k_gate_cat<<<2560, 256, 0, stream>>>(gepre, ge1_b, ge2_b, embs0, emb_avg,
                                       embs, c_t, rnnin_bf);

  // GRU layer 0
  k_gemm<0><<<dim3(1, 48, 5), 256, 0, stream>>>(rnnin_bf, wih0, gi0, nullptr,
                                                3072, 2560, 16, 80, 1);
  k_gemm<0><<<dim3(1, 48, 4), 256, 0, stream>>>(h0_bf, whh0, gh0, nullptr,
                                                3072, 1024, 8, 32, 1);
  k_gru<<<1024, 256, 0, stream>>>(gi0, gh0, bih0, bhh0, h0, out_h1_0, h1_0_bf);
  // GRU layer 1
  k_gemm<0><<<dim3(1, 48, 4), 256, 0, stream>>>(h1_0_bf, wih1, gi1, nullptr,
                                                3072, 1024, 8, 32, 1);
  k_gemm<0><<<dim3(1, 48, 4), 256, 0, stream>>>(h0_bf + 262144, whh1, gh1, nullptr,
                                                3072, 1024, 8, 32, 1);
  k_gru<<<1024, 256, 0, stream>>>(gi1, gh1, bih1, bhh1, h0 + 262144, out_h1_1, nullptr);

  // bottleneck + output projection
  k_cat_bn0<<<3584, 256, 0, stream>>>(out_h1_1, c_t, embs, bn0in_bf);
  k_gemm<1><<<dim3(1, 8, 16), 256, 0, stream>>>(bn0in_bf, bn0_w, bn0pre, nullptr,
                                                512, 3584, 7, 112, 1);
  k_bn0<<<512, 256, 0, stream>>>(bn0pre, bn0_b, b0_bf);
  k_gemm<1><<<dim3(1, 500, 1), 256, 0, stream>>>(b0_bf, bn1_w, out_pred, bn1_b,
                                                 32000, 512, 16, 16, 0);
  k_mask<<<8, 256, 0, stream>>>(maskp, out_pred);
}